// Round 10
// baseline (85.156 us; speedup 1.0000x reference)
//
#include <hip/hip_runtime.h>

// ThinPlateSpline: out = K_query @ rbf_weights + P_query @ poly_coeffs
//   K_ij = r*ln(r), r = ||u_i - c_j|| (d=3)
//   kk = sqrt(r2) * log2(r2) * C, C = 0.5*ln2 folded into staged weights.
//   r2 = usq + |c|^2 - 2 u.c (expanded form), fmax guard for cancellation.
//
// R10: single-variable experiment on the R7 kernel (best, kernel ~33us):
// replace ONLY v_sqrt_f32 with a 7-instr soft sqrt (rsqrt bit-hack + one
// Newton step, rel err 1.7e-3 -- numerics validated in R6). If trans issue
// cost is ~27 cyc/wave64, this saves ~2x13 cyc of the 155-cyc j-iter ->
// kernel ~27us. If trans is ~16 cyc, neutral. Clean discriminator.
// Structure identical to R7: BLK=256 = 4 waves = 4 in-block n-splits of the
// same 128 queries (QPT=2); JCHUNK=256 -> grid (128,16) = 2048 blocks = 8
// blocks/CU = 32 waves/CU. In-block LDS reduction, then coalesced atomics
// across grid.y=16 (786K coalesced atomics ~ 3 MB HBM, proven cheap).

#define BLK 256
#define NS 4            // waves per block = in-block n-splits
#define QPT 2           // queries per lane
#define QPB 128         // queries per block = 64 * QPT
#define JCHUNK 256      // j per block
#define JW (JCHUNK / NS)

__global__ __launch_bounds__(BLK, 8) void tps_kernel(
    const float* __restrict__ u,     // (batch, 3)
    const float* __restrict__ cp,    // (n, 3)
    const float* __restrict__ w,     // (n, 3)
    const float* __restrict__ poly,  // (4, 3)
    float* __restrict__ out,         // (batch, 3)
    int batch, int n)
{
    __shared__ float4 s_a[JCHUNK];         // {-2cx, -2cy, -2cz, |c|^2}
    __shared__ float4 s_b[JCHUNK];         // {C*w, 0}
    __shared__ float  s_red[NS][QPB * 3];  // per-wave partial sums (6 KB)

    const float C = 0.34657359027997264f;  // 0.5 * ln(2)

    const int tid = threadIdx.x;
    const int j0 = blockIdx.y * JCHUNK;

    {   // stage + transform this block's 256-j slice (BLK == JCHUNK)
        const int g = j0 + tid;
        const float cx = cp[g * 3 + 0], cy = cp[g * 3 + 1], cz = cp[g * 3 + 2];
        s_a[tid] = make_float4(-2.f * cx, -2.f * cy, -2.f * cz,
                               fmaf(cx, cx, fmaf(cy, cy, cz * cz)));
        s_b[tid] = make_float4(C * w[g * 3 + 0], C * w[g * 3 + 1],
                               C * w[g * 3 + 2], 0.f);
    }
    __syncthreads();

    const int lane = tid & 63;
    const int wv   = tid >> 6;    // 0..3 = n-split

    float ux[QPT], uy[QPT], uz[QPT], usq[QPT];
    float ax[QPT], ay[QPT], az[QPT];
#pragma unroll
    for (int k = 0; k < QPT; ++k) {
        const int q = blockIdx.x * QPB + k * 64 + lane;  // exact multiple
        ux[k] = u[q * 3 + 0];
        uy[k] = u[q * 3 + 1];
        uz[k] = u[q * 3 + 2];
        usq[k] = fmaf(ux[k], ux[k], fmaf(uy[k], uy[k], uz[k] * uz[k]));
        ax[k] = ay[k] = az[k] = 0.f;
    }

    if (blockIdx.y == 0 && wv == 0) {  // polynomial term exactly once
#pragma unroll
        for (int k = 0; k < QPT; ++k) {
            ax[k] = poly[0] + ux[k] * poly[3] + uy[k] * poly[6] + uz[k] * poly[9];
            ay[k] = poly[1] + ux[k] * poly[4] + uy[k] * poly[7] + uz[k] * poly[10];
            az[k] = poly[2] + ux[k] * poly[5] + uy[k] * poly[8] + uz[k] * poly[11];
        }
    }

    const int jlo = wv * JW;
#pragma unroll 4
    for (int j = jlo; j < jlo + JW; ++j) {
        const float4 A = s_a[j];   // wave-uniform broadcast, ds_read_b128
        const float4 B = s_b[j];
#pragma unroll
        for (int k = 0; k < QPT; ++k) {
            float r2 = fmaf(A.x, ux[k],
                       fmaf(A.y, uy[k],
                       fmaf(A.z, uz[k], A.w + usq[k])));
            r2 = fmaxf(r2, 1e-30f);
            // soft sqrt: rsqrt bit-hack + 1 Newton; sq = r2 * y ~ sqrt(r2)
            float y = __int_as_float(0x5f3759df - (__float_as_int(r2) >> 1));
            y = y * fmaf(-0.5f * r2, y * y, 1.5f);
            const float kk = (r2 * y) * __builtin_amdgcn_logf(r2);
            ax[k] = fmaf(kk, B.x, ax[k]);
            ay[k] = fmaf(kk, B.y, ay[k]);
            az[k] = fmaf(kk, B.z, az[k]);
        }
    }

    // In-block reduction across the 4 n-split waves.
#pragma unroll
    for (int k = 0; k < QPT; ++k) {
        const int base = (k * 64 + lane) * 3;
        s_red[wv][base + 0] = ax[k];
        s_red[wv][base + 1] = ay[k];
        s_red[wv][base + 2] = az[k];
    }
    __syncthreads();

    for (int v = tid; v < QPB * 3; v += BLK) {
        float s = s_red[0][v] + s_red[1][v] + s_red[2][v] + s_red[3][v];
        atomicAdd(&out[(size_t)blockIdx.x * (QPB * 3) + v], s);
    }
}

extern "C" void kernel_launch(void* const* d_in, const int* in_sizes, int n_in,
                              void* d_out, int out_size, void* d_ws, size_t ws_size,
                              hipStream_t stream) {
    const float* u    = (const float*)d_in[0];  // (batch,3)
    const float* cp   = (const float*)d_in[1];  // (n,3)
    const float* w    = (const float*)d_in[2];  // (n,3)
    const float* poly = (const float*)d_in[3];  // (4,3)
    float* out = (float*)d_out;

    const int batch = in_sizes[0] / 3;  // 16384
    const int n     = in_sizes[1] / 3;  // 4096

    hipMemsetAsync(d_out, 0, (size_t)out_size * sizeof(float), stream);

    dim3 block(BLK);
    dim3 grid(batch / QPB, n / JCHUNK);  // (128, 16) = 2048 blocks
    tps_kernel<<<grid, block, 0, stream>>>(u, cp, w, poly, out, batch, n);
}

// Round 11
// 83.348 us; speedup vs baseline: 1.0217x; 1.0217x over previous
//
#include <hip/hip_runtime.h>

// ThinPlateSpline: out = K_query @ rbf_weights + P_query @ poly_coeffs
//   K_ij = r*ln(r), r = ||u_i - c_j|| (d=3)
//   kk = sqrt(r2) * log2(r2) * C, C = 0.5*ln2 folded into packed weights.
//   r2 = usq + |c|^2 - 2 u.c (expanded form), fmax guard.
//
// R11: single structural change vs R7 (best, kernel ~33us): move j-data
// delivery from the LDS pipe (per-CU, shared by 4 SIMDs -- modeled ~20us
// of CU-level ds_read_b128 time) to the SCALAR pipe via forced
// s_load_dwordx16 inline asm. Pack kernel writes 32-B records
// {-2cx,-2cy,-2cz,|c|^2, C*wx,C*wy,C*wz,0}; main loop fetches 4 records
// (128 B) per lgkmcnt(0) wait => ~272 VALU cyc per SMEM round trip.
// LDS now only the 6 KB reduction array; staging + its barrier deleted.
// Rest identical to R7: QPT=2, BLK=256 (4 waves = 4 n-splits), grid
// (128,16) = 8 blocks/CU = 32 waves/CU, coalesced atomics across grid.y.

#define BLK 256
#define NS 4            // waves per block = in-block n-splits
#define QPT 2           // queries per lane
#define QPB 128         // queries per block = 64 * QPT
#define JCHUNK 256      // j per block
#define JW (JCHUNK / NS)

typedef __attribute__((ext_vector_type(16))) int v16i;

__global__ void pack_kernel(const float* __restrict__ cp,
                            const float* __restrict__ w,
                            float* __restrict__ pack, int n) {
    const int j = blockIdx.x * blockDim.x + threadIdx.x;
    if (j >= n) return;
    const float C = 0.34657359027997264f;  // 0.5 * ln(2)
    const float cx = cp[j * 3 + 0], cy = cp[j * 3 + 1], cz = cp[j * 3 + 2];
    pack[j * 8 + 0] = -2.f * cx;
    pack[j * 8 + 1] = -2.f * cy;
    pack[j * 8 + 2] = -2.f * cz;
    pack[j * 8 + 3] = fmaf(cx, cx, fmaf(cy, cy, cz * cz));
    pack[j * 8 + 4] = C * w[j * 3 + 0];
    pack[j * 8 + 5] = C * w[j * 3 + 1];
    pack[j * 8 + 6] = C * w[j * 3 + 2];
    pack[j * 8 + 7] = 0.f;
}

__global__ __launch_bounds__(BLK, 8) void tps_kernel(
    const float* __restrict__ u,     // (batch, 3)
    const float* __restrict__ pack,  // (n, 8) packed records
    const float* __restrict__ poly,  // (4, 3)
    float* __restrict__ out,         // (batch, 3)
    int batch, int n)
{
    __shared__ float s_red[NS][QPB * 3];  // per-wave partial sums (6 KB)

    const int tid  = threadIdx.x;
    const int lane = tid & 63;
    const int wv   = __builtin_amdgcn_readfirstlane(tid >> 6);  // 0..3

    float ux[QPT], uy[QPT], uz[QPT], usq[QPT];
    float ax[QPT], ay[QPT], az[QPT];
#pragma unroll
    for (int k = 0; k < QPT; ++k) {
        const int q = blockIdx.x * QPB + k * 64 + lane;  // exact multiple
        ux[k] = u[q * 3 + 0];
        uy[k] = u[q * 3 + 1];
        uz[k] = u[q * 3 + 2];
        usq[k] = fmaf(ux[k], ux[k], fmaf(uy[k], uy[k], uz[k] * uz[k]));
        ax[k] = ay[k] = az[k] = 0.f;
    }

    if (blockIdx.y == 0 && wv == 0) {  // polynomial term exactly once
#pragma unroll
        for (int k = 0; k < QPT; ++k) {
            ax[k] = poly[0] + ux[k] * poly[3] + uy[k] * poly[6] + uz[k] * poly[9];
            ay[k] = poly[1] + ux[k] * poly[4] + uy[k] * poly[7] + uz[k] * poly[10];
            az[k] = poly[2] + ux[k] * poly[5] + uy[k] * poly[8] + uz[k] * poly[11];
        }
    }

    const int jlo = blockIdx.y * JCHUNK + wv * JW;
    const float* pj = pack + (size_t)jlo * 8;  // block/wave-uniform

    for (int jj = 0; jj < JW; jj += 4) {
        // 4 records = 128 B on the scalar pipe; one lgkmcnt wait per 8 pairs.
        v16i d0, d1;
        asm volatile("s_load_dwordx16 %0, %2, 0x0\n\t"
                     "s_load_dwordx16 %1, %2, 0x40\n\t"
                     "s_waitcnt lgkmcnt(0)"
                     : "=s"(d0), "=s"(d1)
                     : "s"(pj + (size_t)jj * 8)
                     : "memory");
#pragma unroll
        for (int r = 0; r < 4; ++r) {
            const v16i& d = (r < 2) ? d0 : d1;
            const int o = (r & 1) * 8;
            const float m2x = __int_as_float(d[o + 0]);
            const float m2y = __int_as_float(d[o + 1]);
            const float m2z = __int_as_float(d[o + 2]);
            const float c2  = __int_as_float(d[o + 3]);
            const float wx  = __int_as_float(d[o + 4]);
            const float wy  = __int_as_float(d[o + 5]);
            const float wz  = __int_as_float(d[o + 6]);
#pragma unroll
            for (int k = 0; k < QPT; ++k) {
                float r2 = fmaf(m2x, ux[k],
                           fmaf(m2y, uy[k],
                           fmaf(m2z, uz[k], c2 + usq[k])));
                r2 = fmaxf(r2, 1e-30f);
                const float kk = __builtin_amdgcn_sqrtf(r2) *
                                 __builtin_amdgcn_logf(r2);
                ax[k] = fmaf(kk, wx, ax[k]);
                ay[k] = fmaf(kk, wy, ay[k]);
                az[k] = fmaf(kk, wz, az[k]);
            }
        }
    }

    // In-block reduction across the 4 n-split waves.
#pragma unroll
    for (int k = 0; k < QPT; ++k) {
        const int base = (k * 64 + lane) * 3;
        s_red[wv][base + 0] = ax[k];
        s_red[wv][base + 1] = ay[k];
        s_red[wv][base + 2] = az[k];
    }
    __syncthreads();

    for (int v = tid; v < QPB * 3; v += BLK) {
        float s = s_red[0][v] + s_red[1][v] + s_red[2][v] + s_red[3][v];
        atomicAdd(&out[(size_t)blockIdx.x * (QPB * 3) + v], s);
    }
}

extern "C" void kernel_launch(void* const* d_in, const int* in_sizes, int n_in,
                              void* d_out, int out_size, void* d_ws, size_t ws_size,
                              hipStream_t stream) {
    const float* u    = (const float*)d_in[0];  // (batch,3)
    const float* cp   = (const float*)d_in[1];  // (n,3)
    const float* w    = (const float*)d_in[2];  // (n,3)
    const float* poly = (const float*)d_in[3];  // (4,3)
    float* out  = (float*)d_out;
    float* pack = (float*)d_ws;                 // n * 8 floats = 128 KB

    const int batch = in_sizes[0] / 3;  // 16384
    const int n     = in_sizes[1] / 3;  // 4096

    pack_kernel<<<(n + 255) / 256, 256, 0, stream>>>(cp, w, pack, n);

    hipMemsetAsync(d_out, 0, (size_t)out_size * sizeof(float), stream);

    dim3 block(BLK);
    dim3 grid(batch / QPB, n / JCHUNK);  // (128, 16) = 2048 blocks
    tps_kernel<<<grid, block, 0, stream>>>(u, pack, poly, out, batch, n);
}

// Round 12
// 80.173 us; speedup vs baseline: 1.0621x; 1.0396x over previous
//
#include <hip/hip_runtime.h>

// ThinPlateSpline: out = K_query @ rbf_weights + P_query @ poly_coeffs
//   K_ij = r*ln(r), r = ||u_i - c_j|| (d=3)
//   kk = sqrt(r2) * log2(r2) * C, C = 0.5*ln2 folded into staged weights.
//   r2 = usq + |c|^2 - 2 u.c (expanded form), fmax guard for cancellation.
//
// R12: consolidated model says the kernel is LATENCY-bound (hw trans hidden
// on its own pipe, VALU ~35% occupied); perf tracks independent chains per
// SIMD (16 chains -> ~33us across all delivery variants). This round: 32
// chains/SIMD = QPT=4 x 8 waves/SIMD simultaneously (R9 had QPT=4 at half
// occupancy; R7 had full occupancy at QPT=2). JCHUNK=128 -> grid (64,32) =
// 2048 blocks = 8 blocks/CU. hw sqrt+log (R10 proved soft-sqrt regresses).
// LDS delivery (best tested), in-block reduction, coalesced atomics.

#define BLK 256
#define NS 4            // waves per block = in-block n-splits
#define QPT 4           // queries per lane (4 independent chains)
#define QPB 256         // queries per block = 64 * QPT
#define JCHUNK 128      // j per block
#define JW (JCHUNK / NS)

__global__ __launch_bounds__(BLK, 8) void tps_kernel(
    const float* __restrict__ u,     // (batch, 3)
    const float* __restrict__ cp,    // (n, 3)
    const float* __restrict__ w,     // (n, 3)
    const float* __restrict__ poly,  // (4, 3)
    float* __restrict__ out,         // (batch, 3)
    int batch, int n)
{
    __shared__ float4 s_a[JCHUNK];         // {-2cx, -2cy, -2cz, |c|^2}
    __shared__ float4 s_b[JCHUNK];         // {C*w, 0}  (4 KB total a+b)
    __shared__ float  s_red[NS][QPB * 3];  // per-wave partials (12 KB)

    const float C = 0.34657359027997264f;  // 0.5 * ln(2)

    const int tid = threadIdx.x;
    const int j0 = blockIdx.y * JCHUNK;

    if (tid < JCHUNK) {  // stage + transform this block's 128-j slice
        const int g = j0 + tid;
        const float cx = cp[g * 3 + 0], cy = cp[g * 3 + 1], cz = cp[g * 3 + 2];
        s_a[tid] = make_float4(-2.f * cx, -2.f * cy, -2.f * cz,
                               fmaf(cx, cx, fmaf(cy, cy, cz * cz)));
        s_b[tid] = make_float4(C * w[g * 3 + 0], C * w[g * 3 + 1],
                               C * w[g * 3 + 2], 0.f);
    }
    __syncthreads();

    const int lane = tid & 63;
    const int wv   = tid >> 6;    // 0..3 = n-split

    float ux[QPT], uy[QPT], uz[QPT], usq[QPT];
    float ax[QPT], ay[QPT], az[QPT];
#pragma unroll
    for (int k = 0; k < QPT; ++k) {
        const int q = blockIdx.x * QPB + k * 64 + lane;  // exact multiple
        ux[k] = u[q * 3 + 0];
        uy[k] = u[q * 3 + 1];
        uz[k] = u[q * 3 + 2];
        usq[k] = fmaf(ux[k], ux[k], fmaf(uy[k], uy[k], uz[k] * uz[k]));
        ax[k] = ay[k] = az[k] = 0.f;
    }

    if (blockIdx.y == 0 && wv == 0) {  // polynomial term exactly once
#pragma unroll
        for (int k = 0; k < QPT; ++k) {
            ax[k] = poly[0] + ux[k] * poly[3] + uy[k] * poly[6] + uz[k] * poly[9];
            ay[k] = poly[1] + ux[k] * poly[4] + uy[k] * poly[7] + uz[k] * poly[10];
            az[k] = poly[2] + ux[k] * poly[5] + uy[k] * poly[8] + uz[k] * poly[11];
        }
    }

    const int jlo = wv * JW;
#pragma unroll 2
    for (int j = jlo; j < jlo + JW; ++j) {
        const float4 A = s_a[j];   // wave-uniform broadcast, ds_read_b128
        const float4 B = s_b[j];
#pragma unroll
        for (int k = 0; k < QPT; ++k) {   // 4 independent chains
            float r2 = fmaf(A.x, ux[k],
                       fmaf(A.y, uy[k],
                       fmaf(A.z, uz[k], A.w + usq[k])));
            r2 = fmaxf(r2, 1e-30f);
            const float kk = __builtin_amdgcn_sqrtf(r2) *
                             __builtin_amdgcn_logf(r2);
            ax[k] = fmaf(kk, B.x, ax[k]);
            ay[k] = fmaf(kk, B.y, ay[k]);
            az[k] = fmaf(kk, B.z, az[k]);
        }
    }

    // In-block reduction across the 4 n-split waves.
#pragma unroll
    for (int k = 0; k < QPT; ++k) {
        const int base = (k * 64 + lane) * 3;
        s_red[wv][base + 0] = ax[k];
        s_red[wv][base + 1] = ay[k];
        s_red[wv][base + 2] = az[k];
    }
    __syncthreads();

    for (int v = tid; v < QPB * 3; v += BLK) {
        float s = s_red[0][v] + s_red[1][v] + s_red[2][v] + s_red[3][v];
        atomicAdd(&out[(size_t)blockIdx.x * (QPB * 3) + v], s);
    }
}

extern "C" void kernel_launch(void* const* d_in, const int* in_sizes, int n_in,
                              void* d_out, int out_size, void* d_ws, size_t ws_size,
                              hipStream_t stream) {
    const float* u    = (const float*)d_in[0];  // (batch,3)
    const float* cp   = (const float*)d_in[1];  // (n,3)
    const float* w    = (const float*)d_in[2];  // (n,3)
    const float* poly = (const float*)d_in[3];  // (4,3)
    float* out = (float*)d_out;

    const int batch = in_sizes[0] / 3;  // 16384
    const int n     = in_sizes[1] / 3;  // 4096

    hipMemsetAsync(d_out, 0, (size_t)out_size * sizeof(float), stream);

    dim3 block(BLK);
    dim3 grid(batch / QPB, n / JCHUNK);  // (64, 32) = 2048 blocks
    tps_kernel<<<grid, block, 0, stream>>>(u, cp, w, poly, out, batch, n);
}

// Round 13
// 78.856 us; speedup vs baseline: 1.0799x; 1.0167x over previous
//
#include <hip/hip_runtime.h>

// ThinPlateSpline: out = K_query @ rbf_weights + P_query @ poly_coeffs
//   K_ij = r*ln(r), r = ||u_i - c_j|| (d=3)
//   kk = sqrt(r2) * log2(r2) * C, C = 0.5*ln2 folded into staged weights.
//
// R13: cross-round fit -> single-pipe throughput bound: ~22 VALU instr/pair
// + 2 trans @ ~16cyc on the same pipe (~76 cyc/pair-wave = 32.4us; matches
// R7/R12 measured 33us). Attack the VALU half with CDNA packed FP32
// (v_pk_fma_f32 etc., VOP3P: 2 FP32 ops / 2-cyc instr). LDS records are
// PRE-DUPLICATED ({ax,ax,ay,ay}...) so packed operands load directly with
// no per-j broadcast movs. QPT=4 = 2 packed v2f groups. Trans stays scalar
// hw sqrt/log (elementwise floor, 2/pair invariant). Structure = R12:
// BLK=256 (4 waves = 4 n-splits), JCHUNK=128, grid (64,32) = 8 blocks/CU,
// in-block LDS reduction, coalesced atomics across grid.y.

typedef float v2f __attribute__((ext_vector_type(2)));
typedef float v4f __attribute__((ext_vector_type(4)));

#define BLK 256
#define NS 4            // waves per block = in-block n-splits
#define QPT 4           // queries per lane = 2 packed groups
#define QPB 256         // queries per block = 64 * QPT
#define JCHUNK 128      // j per block
#define JW (JCHUNK / NS)

__global__ __launch_bounds__(BLK, 8) void tps_kernel(
    const float* __restrict__ u,     // (batch, 3)
    const float* __restrict__ cp,    // (n, 3)
    const float* __restrict__ w,     // (n, 3)
    const float* __restrict__ poly,  // (4, 3)
    float* __restrict__ out,         // (batch, 3)
    int batch, int n)
{
    // Pre-duplicated packed records, 2 x v4f per j each:
    //   s_a4[2j]   = {-2cx,-2cx,-2cy,-2cy}   s_a4[2j+1] = {-2cz,-2cz,c2,c2}
    //   s_b4[2j]   = {Cwx,Cwx,Cwy,Cwy}       s_b4[2j+1] = {Cwz,Cwz,0,0}
    __shared__ v4f s_a4[JCHUNK * 2];
    __shared__ v4f s_b4[JCHUNK * 2];
    __shared__ float s_red[NS][QPB * 3];   // per-wave partials (12 KB)

    const float C = 0.34657359027997264f;  // 0.5 * ln(2)

    const int tid = threadIdx.x;
    const int j0 = blockIdx.y * JCHUNK;

    if (tid < JCHUNK) {  // stage + transform + duplicate this 128-j slice
        const int g = j0 + tid;
        const float cx = cp[g * 3 + 0], cy = cp[g * 3 + 1], cz = cp[g * 3 + 2];
        const float c2 = fmaf(cx, cx, fmaf(cy, cy, cz * cz));
        const float wx = C * w[g * 3 + 0];
        const float wy = C * w[g * 3 + 1];
        const float wz = C * w[g * 3 + 2];
        s_a4[tid * 2 + 0] = (v4f){-2.f * cx, -2.f * cx, -2.f * cy, -2.f * cy};
        s_a4[tid * 2 + 1] = (v4f){-2.f * cz, -2.f * cz, c2, c2};
        s_b4[tid * 2 + 0] = (v4f){wx, wx, wy, wy};
        s_b4[tid * 2 + 1] = (v4f){wz, wz, 0.f, 0.f};
    }
    __syncthreads();

    const int lane = tid & 63;
    const int wv   = tid >> 6;    // 0..3 = n-split

    // 2 packed groups: group g holds queries (2g)*64+lane and (2g+1)*64+lane
    v2f uxv[2], uyv[2], uzv[2], usqv[2];
    v2f axv[2], ayv[2], azv[2];
#pragma unroll
    for (int g = 0; g < 2; ++g) {
        const int qa = blockIdx.x * QPB + (2 * g + 0) * 64 + lane;
        const int qb = blockIdx.x * QPB + (2 * g + 1) * 64 + lane;
        uxv[g] = (v2f){u[qa * 3 + 0], u[qb * 3 + 0]};
        uyv[g] = (v2f){u[qa * 3 + 1], u[qb * 3 + 1]};
        uzv[g] = (v2f){u[qa * 3 + 2], u[qb * 3 + 2]};
        usqv[g] = __builtin_elementwise_fma(uxv[g], uxv[g],
                  __builtin_elementwise_fma(uyv[g], uyv[g], uzv[g] * uzv[g]));
        axv[g] = (v2f){0.f, 0.f};
        ayv[g] = (v2f){0.f, 0.f};
        azv[g] = (v2f){0.f, 0.f};
    }

    if (blockIdx.y == 0 && wv == 0) {  // polynomial term exactly once
#pragma unroll
        for (int g = 0; g < 2; ++g) {
            axv[g] = poly[0] + uxv[g] * poly[3] + uyv[g] * poly[6] + uzv[g] * poly[9];
            ayv[g] = poly[1] + uxv[g] * poly[4] + uyv[g] * poly[7] + uzv[g] * poly[10];
            azv[g] = poly[2] + uxv[g] * poly[5] + uyv[g] * poly[8] + uzv[g] * poly[11];
        }
    }

    const int jlo = wv * JW;
#pragma unroll 2
    for (int j = jlo; j < jlo + JW; ++j) {
        const v4f A0 = s_a4[j * 2 + 0];  // {ax,ax,ay,ay}
        const v4f A1 = s_a4[j * 2 + 1];  // {az,az,c2,c2}
        const v4f B0 = s_b4[j * 2 + 0];  // {wx,wx,wy,wy}
        const v4f B1 = s_b4[j * 2 + 1];  // {wz,wz,0,0}
        const v2f m2x = A0.xy, m2y = A0.zw, m2z = A1.xy, c2v = A1.zw;
        const v2f wxv = B0.xy, wyv = B0.zw, wzv = B1.xy;
#pragma unroll
        for (int g = 0; g < 2; ++g) {
            v2f r2 = __builtin_elementwise_fma(m2x, uxv[g],
                     __builtin_elementwise_fma(m2y, uyv[g],
                     __builtin_elementwise_fma(m2z, uzv[g], c2v + usqv[g])));
            r2 = __builtin_elementwise_max(r2, (v2f){1e-30f, 1e-30f});
            // scalar hw trans per element (elementwise floor: 2 per pair)
            const v2f sq = {__builtin_amdgcn_sqrtf(r2.x),
                            __builtin_amdgcn_sqrtf(r2.y)};
            const v2f lg = {__builtin_amdgcn_logf(r2.x),
                            __builtin_amdgcn_logf(r2.y)};
            const v2f kk = sq * lg;      // v_pk_mul_f32
            axv[g] = __builtin_elementwise_fma(kk, wxv, axv[g]);
            ayv[g] = __builtin_elementwise_fma(kk, wyv, ayv[g]);
            azv[g] = __builtin_elementwise_fma(kk, wzv, azv[g]);
        }
    }

    // In-block reduction across the 4 n-split waves.
#pragma unroll
    for (int g = 0; g < 2; ++g) {
        const int ba = ((2 * g + 0) * 64 + lane) * 3;
        const int bb = ((2 * g + 1) * 64 + lane) * 3;
        s_red[wv][ba + 0] = axv[g].x;  s_red[wv][bb + 0] = axv[g].y;
        s_red[wv][ba + 1] = ayv[g].x;  s_red[wv][bb + 1] = ayv[g].y;
        s_red[wv][ba + 2] = azv[g].x;  s_red[wv][bb + 2] = azv[g].y;
    }
    __syncthreads();

    for (int v = tid; v < QPB * 3; v += BLK) {
        float s = s_red[0][v] + s_red[1][v] + s_red[2][v] + s_red[3][v];
        atomicAdd(&out[(size_t)blockIdx.x * (QPB * 3) + v], s);
    }
}

extern "C" void kernel_launch(void* const* d_in, const int* in_sizes, int n_in,
                              void* d_out, int out_size, void* d_ws, size_t ws_size,
                              hipStream_t stream) {
    const float* u    = (const float*)d_in[0];  // (batch,3)
    const float* cp   = (const float*)d_in[1];  // (n,3)
    const float* w    = (const float*)d_in[2];  // (n,3)
    const float* poly = (const float*)d_in[3];  // (4,3)
    float* out = (float*)d_out;

    const int batch = in_sizes[0] / 3;  // 16384
    const int n     = in_sizes[1] / 3;  // 4096

    hipMemsetAsync(d_out, 0, (size_t)out_size * sizeof(float), stream);

    dim3 block(BLK);
    dim3 grid(batch / QPB, n / JCHUNK);  // (64, 32) = 2048 blocks
    tps_kernel<<<grid, block, 0, stream>>>(u, cp, w, poly, out, batch, n);
}